// Round 1
// baseline (703.725 us; speedup 1.0000x reference)
//
#include <hip/hip_runtime.h>
#include <cstdint>

#define N_NODES 100000
#define N_EDGES 500000
#define N_GRAPHS 128
#define HID 128
#define SCAN1_B ((2 * N_NODES + 255) / 256)   // 782 blocks over concatenated counts
#define N_HALF (N_EDGES / 32)                 // 15625 32-edge segments per layer

typedef __attribute__((ext_vector_type(8))) short short8;
typedef __attribute__((ext_vector_type(4))) float f32x4;

// ---- monotone float<->uint encoding for max; enc==0 marks "never written" ----
__device__ __forceinline__ unsigned encf(float f) {
    unsigned u = __float_as_uint(f);
    return (u & 0x80000000u) ? ~u : (u | 0x80000000u);
}
__device__ __forceinline__ float decf(unsigned e) {
    unsigned u = (e & 0x80000000u) ? (e & 0x7FFFFFFFu) : ~e;
    return __uint_as_float(u);
}
__device__ __forceinline__ unsigned pk_bf16(float a, float b) {
    unsigned ua = __float_as_uint(a);
    unsigned ub = __float_as_uint(b);
    ua = (ua + 0x7fffu + ((ua >> 16) & 1u)) >> 16;
    ub = (ub + 0x7fffu + ((ub >> 16) & 1u)) & 0xffff0000u;
    return ua | ub;
}
__device__ __forceinline__ ushort bf16r(float f) {
    unsigned u = __float_as_uint(f);
    return (ushort)((u + 0x7fffu + ((u >> 16) & 1u)) >> 16);
}
__device__ __forceinline__ float bf2f(ushort h) {
    return __uint_as_float((unsigned)h << 16);
}

// ---- transpose+convert weights -> bf16 [n][k], D computed on the fly;
//      block 384 does the prep (wkey/bias0); blocks >=385 zero cnt + pooled
//      (folds the two hipMemsetAsync dispatches into this launch) ----
__global__ __launch_bounds__(256) void transp_prep_kernel(const float* __restrict__ W1b,
                                                          const float* __restrict__ W2b,
                                                          const float* __restrict__ W1a,
                                                          const float* __restrict__ W2a,
                                                          const float* __restrict__ W_enc,
                                                          const float* __restrict__ b_enc,
                                                          const float* __restrict__ W0,
                                                          const float* __restrict__ b0,
                                                          ushort* __restrict__ WT,
                                                          float* __restrict__ wkey,
                                                          float* __restrict__ bias0,
                                                          int* __restrict__ cnt,
                                                          float* __restrict__ pooled) {
    int blk = blockIdx.x;
    int tid = threadIdx.x;
    if (blk >= 385) {   // zeroing duty: 782 blocks for cnt, 256 for pooled
        int z = blk - 385;
        if (z < SCAN1_B) {
            int i = z * 256 + tid;
            if (i < 2 * N_NODES) cnt[i] = 0;
        } else {
            int i = (z - SCAN1_B) * 256 + tid;   // exactly 128*512 = 65536 floats
            pooled[i] = 0.f;
        }
        return;
    }
    if (blk == 384) {   // prep
        if (tid < HID) {
            float wk = 0.f, bk = b0[tid];
            for (int k = 0; k < 32; ++k) {
                float w = W0[(15 + k) * HID + tid];
                wk += W_enc[k] * w;
                bk += b_enc[k] * w;
            }
            wkey[tid] = wk;
            bias0[tid] = bk;
        }
        return;
    }
    int m = blk >> 6;
    int i = (blk & 63) * 256 + tid;   // i = n*128 + k
    int n = i >> 7, k = i & 127;
    int src = k * HID + n;
    float v;
    switch (m) {
        case 0: v = W1b[src]; break;
        case 1: v = W2b[src]; break;
        case 2: v = W1a[src]; break;
        case 3: v = W1a[HID * HID + src] - W1a[src]; break;
        case 4: v = W2a[src]; break;
        default: v = W2a[HID * HID + src] - W2a[src]; break;
    }
    WT[m * HID * HID + i] = bf16r(v);
}

// ---- encoder: h = relu(features @ W0[0:15] + key*wkey + bias0) -> bf16 ----
__global__ __launch_bounds__(256) void encode_kernel(const float* __restrict__ x,
                                                     const float* __restrict__ W0,
                                                     const float* __restrict__ wkey,
                                                     const float* __restrict__ bias0,
                                                     ushort* __restrict__ h) {
    int n = blockIdx.x * 2 + (threadIdx.x >> 7);
    int j = threadIdx.x & 127;
    const float* xr = x + n * 16;
    float acc = bias0[j] + xr[0] * wkey[j];
#pragma unroll
    for (int f = 0; f < 15; ++f)
        acc = fmaf(xr[1 + f], W0[f * HID + j], acc);
    h[n * HID + j] = bf16r(fmaxf(acc, 0.f));
}

// ---- dual MFMA (N x 128 bf16) @ (128 x 128) -> bf16, LDS-restaged epilogue ----
// Optional fused combine (aggin u32-encoded): A-tile element becomes
// x1 = relu((cnt>0 ? dec(agg)+badd : 0) + h), also written to xout.
__global__ __launch_bounds__(256, 4) void mm_mfma_dual_kernel(const ushort* __restrict__ in,
                                                              const unsigned* __restrict__ aggin,
                                                              const int* __restrict__ cntin,
                                                              const float* __restrict__ baddin,
                                                              ushort* __restrict__ xout,
                                                              const ushort* __restrict__ WuT,
                                                              const ushort* __restrict__ WvT,
                                                              const float* __restrict__ bv,
                                                              ushort* __restrict__ outu,
                                                              ushort* __restrict__ outv, int nrows) {
    __shared__ ushort sH[128 * 136];   // A-tile, then reused for D-restage
    int tid = threadIdx.x;
    int n0 = blockIdx.x * 128;
#pragma unroll
    for (int q = 0; q < 8; ++q) {
        int c = q * 256 + tid;
        int r = c >> 4, off = (c & 15) << 3;
        int n = n0 + r;
        uint4 vv = make_uint4(0, 0, 0, 0);
        if (n < nrows) {
            uint4 hv = *(const uint4*)(in + (size_t)n * HID + off);
            if (aggin) {
                float add[8];
#pragma unroll
                for (int p = 0; p < 8; ++p) add[p] = 0.f;
                if (cntin[n] > 0) {
                    uint4 e0 = *(const uint4*)(aggin + (size_t)n * HID + off);
                    uint4 e1 = *(const uint4*)(aggin + (size_t)n * HID + off + 4);
                    float4 bb0 = *(const float4*)(baddin + off);
                    float4 bb1 = *(const float4*)(baddin + off + 4);
                    add[0] = decf(e0.x) + bb0.x; add[1] = decf(e0.y) + bb0.y;
                    add[2] = decf(e0.z) + bb0.z; add[3] = decf(e0.w) + bb0.w;
                    add[4] = decf(e1.x) + bb1.x; add[5] = decf(e1.y) + bb1.y;
                    add[6] = decf(e1.z) + bb1.z; add[7] = decf(e1.w) + bb1.w;
                }
                unsigned hw[4] = {hv.x, hv.y, hv.z, hv.w};
                unsigned ow[4];
#pragma unroll
                for (int p = 0; p < 4; ++p) {
                    float lo = __uint_as_float(hw[p] << 16);
                    float hi = __uint_as_float(hw[p] & 0xffff0000u);
                    float r0 = fmaxf(add[2 * p] + lo, 0.f);
                    float r1 = fmaxf(add[2 * p + 1] + hi, 0.f);
                    ow[p] = pk_bf16(r0, r1);
                }
                vv = make_uint4(ow[0], ow[1], ow[2], ow[3]);
                *(uint4*)(xout + (size_t)n * HID + off) = vv;
            } else {
                vv = hv;
            }
        }
        *(uint4*)(sH + r * 136 + off) = vv;
    }
    __syncthreads();

    int lane = tid & 63, wv = tid >> 6;
    int l15 = lane & 15, quad = lane >> 4;

    short8 afr[2][4];
#pragma unroll
    for (int rr = 0; rr < 2; ++rr) {
        const ushort* ab = sH + (wv * 32 + rr * 16 + l15) * 136 + quad * 8;
#pragma unroll
        for (int kc = 0; kc < 4; ++kc)
            afr[rr][kc] = *(const short8*)(ab + kc * 32);
    }

#pragma unroll
    for (int pass = 0; pass < 2; ++pass) {
        const ushort* WT = pass ? WvT : WuT;
        ushort* out = pass ? outv : outu;
        f32x4 acc[2][8];
#pragma unroll
        for (int rr = 0; rr < 2; ++rr)
#pragma unroll
            for (int ct = 0; ct < 8; ++ct) acc[rr][ct] = (f32x4){0.f, 0.f, 0.f, 0.f};
#pragma unroll
        for (int kc = 0; kc < 4; ++kc) {
#pragma unroll
            for (int ct = 0; ct < 8; ++ct) {
                short8 bfr = *(const short8*)(WT + (ct * 16 + l15) * 128 + quad * 8 + kc * 32);
                acc[0][ct] = __builtin_amdgcn_mfma_f32_16x16x32_bf16(afr[0][kc], bfr, acc[0][ct], 0, 0, 0);
                acc[1][ct] = __builtin_amdgcn_mfma_f32_16x16x32_bf16(afr[1][kc], bfr, acc[1][ct], 0, 0, 0);
            }
        }
        __syncthreads();
#pragma unroll
        for (int ct = 0; ct < 8; ++ct) {
            int col = ct * 16 + l15;
            float bb = pass ? bv[col] : 0.f;
#pragma unroll
            for (int rr = 0; rr < 2; ++rr) {
                int rowb = wv * 32 + rr * 16 + quad * 4;
#pragma unroll
                for (int reg = 0; reg < 4; ++reg)
                    sH[(rowb + reg) * 136 + col] = bf16r(acc[rr][ct][reg] + bb);
            }
        }
        __syncthreads();
#pragma unroll
        for (int q = 0; q < 8; ++q) {
            int c = q * 256 + tid;
            int r = c >> 4, off = (c & 15) << 3;
            int m = n0 + r;
            if (m < nrows)
                *(uint4*)(out + (size_t)m * HID + off) = *(const uint4*)(sH + r * 136 + off);
        }
    }
}

// ---- merged CSR build for BOTH layers ----
__global__ __launch_bounds__(256) void hist_kernel(const int* __restrict__ dst1,
                                                   const int* __restrict__ dst2,
                                                   int* __restrict__ cnt) {
    int e = blockIdx.x * 256 + threadIdx.x;
    if (e < N_EDGES) atomicAdd(&cnt[dst1[e]], 1);
    else if (e < 2 * N_EDGES) atomicAdd(&cnt[N_NODES + dst2[e - N_EDGES]], 1);
}

__global__ __launch_bounds__(256) void scan1_kernel(const int* __restrict__ cnt,
                                                    int* __restrict__ cursor,
                                                    int* __restrict__ partials) {
    __shared__ int tmp[256];
    int tid = threadIdx.x;
    int gid = blockIdx.x * 256 + tid;
    int v = (gid < 2 * N_NODES) ? cnt[gid] : 0;
    tmp[tid] = v;
    __syncthreads();
#pragma unroll
    for (int off = 1; off < 256; off <<= 1) {
        int t = (tid >= off) ? tmp[tid - off] : 0;
        __syncthreads();
        tmp[tid] += t;
        __syncthreads();
    }
    if (gid < 2 * N_NODES) cursor[gid] = tmp[tid] - v;   // local exclusive
    if (tid == 255) partials[blockIdx.x] = tmp[255];
}

__global__ __launch_bounds__(1024) void scan2_kernel(int* __restrict__ partials) {
    __shared__ int tmp[1024];
    int tid = threadIdx.x;
    int v = (tid < SCAN1_B) ? partials[tid] : 0;
    tmp[tid] = v;
    __syncthreads();
#pragma unroll
    for (int off = 1; off < 1024; off <<= 1) {
        int t = (tid >= off) ? tmp[tid - off] : 0;
        __syncthreads();
        tmp[tid] += t;
        __syncthreads();
    }
    if (tid < SCAN1_B) partials[tid] = tmp[tid] - v;  // exclusive
}

__global__ __launch_bounds__(256) void scatter_kernel(const int* __restrict__ src1,
                                                      const int* __restrict__ dst1,
                                                      const int* __restrict__ src2,
                                                      const int* __restrict__ dst2,
                                                      int* __restrict__ cursor,
                                                      const int* __restrict__ partials,
                                                      int2* __restrict__ pedge) {
    int e = blockIdx.x * 256 + threadIdx.x;
    if (e < N_EDGES) {
        int d = dst1[e];
        int pos = atomicAdd(&cursor[d], 1) + partials[d >> 8];
        pedge[pos] = make_int2(src1[e], d);
    } else if (e < 2 * N_EDGES) {
        int d = dst2[e - N_EDGES];
        int idx = N_NODES + d;
        int pos = atomicAdd(&cursor[idx], 1) + partials[idx >> 8];
        pedge[pos] = make_int2(src2[e - N_EDGES], d);   // pos lands in [N_EDGES, 2*N_EDGES)
    }
}

// ---- zero boundary agg rows for BOTH layers in one launch (u32 arrays) ----
__global__ __launch_bounds__(256) void zbound_both_kernel(const int2* __restrict__ pedge,
                                                          unsigned* __restrict__ agg1,
                                                          unsigned* __restrict__ agg2) {
    int b = blockIdx.x * 4 + (threadIdx.x >> 6);
    int lane = threadIdx.x & 63;
    if (b >= 2 * N_HALF) return;
    int layer = b >= N_HALF;
    int bl = b - layer * N_HALF;
    const int2* pe = pedge + (size_t)layer * N_EDGES;
    unsigned* agg = layer ? agg2 : agg1;
    int d;
    if (bl == 0) {
        d = pe[N_EDGES - 1].y;               // tail row (clamped duplicates -> atomics)
    } else {
        int da = pe[bl * 32 - 1].y, db = pe[bl * 32].y;
        if (da != db) return;
        d = db;
    }
    *(uint2*)(agg + (size_t)d * HID + lane * 2) = make_uint2(0u, 0u);
}

// ---- edge conv: bf16 MFMA, 128-edge dst-sorted windows, 512 threads ----
// v2: no LDS W-tile (B-fragments read from global, L1/L2-resident 32KB);
//     waves own 32 edges x 64 cols so each B-frag load feeds 2 MFMAs;
//     per-thread pedge meta (first barrier removed); LDS = sU + sDst only
//     -> ~35 KB -> 3 blocks/CU at __launch_bounds__(512,6).
__global__ __launch_bounds__(512, 6) void edge_kernel(const ushort* __restrict__ u,
                                                      const ushort* __restrict__ v,
                                                      const float* __restrict__ x,
                                                      const int2* __restrict__ pedge,
                                                      const ushort* __restrict__ WbT,
                                                      const float* __restrict__ wlast,
                                                      unsigned* __restrict__ agg) {
    __shared__ ushort sU[128 * 136];    // union: t[128][136] then msgT[128][132]
    __shared__ int sDst[128];
    int tid = threadIdx.x;
    int w0 = blockIdx.x * 128;

    // phase 1: 4 threads/edge, 32 cols each; meta from per-thread pedge loads
    {
        int eloc = tid >> 2;
        int kb = (tid & 3) << 5;
        int e = w0 + eloc;
        if (e >= N_EDGES) e = N_EDGES - 1;   // clamp: idempotent under max (tail row pre-zeroed)
        int2 sd = pedge[e];
        if ((tid & 3) == 0) sDst[eloc] = sd.y;
        float kd = x[(size_t)sd.x * 16] - x[(size_t)sd.y * 16];
        const uint4* ur = (const uint4*)(u + (size_t)sd.x * HID + kb);
        const uint4* vr = (const uint4*)(v + (size_t)sd.y * HID + kb);
        uint4 uu[4], vv[4];
#pragma unroll
        for (int q = 0; q < 4; ++q) uu[q] = ur[q];
#pragma unroll
        for (int q = 0; q < 4; ++q) vv[q] = vr[q];
        const float4* wr4 = (const float4*)(wlast + kb);
        uint4* tout = (uint4*)(sU + eloc * 136 + kb);
#pragma unroll
        for (int q = 0; q < 4; ++q) {
            float4 wa = wr4[2 * q], wb = wr4[2 * q + 1];
            float w[8] = {wa.x, wa.y, wa.z, wa.w, wb.x, wb.y, wb.z, wb.w};
            unsigned pu[4] = {uu[q].x, uu[q].y, uu[q].z, uu[q].w};
            unsigned pv[4] = {vv[q].x, vv[q].y, vv[q].z, vv[q].w};
            unsigned pk[4];
#pragma unroll
            for (int p = 0; p < 4; ++p) {
                float a0 = __uint_as_float(pu[p] << 16) + __uint_as_float(pv[p] << 16);
                float a1 = __uint_as_float(pu[p] & 0xffff0000u) + __uint_as_float(pv[p] & 0xffff0000u);
                a0 = fmaf(kd, w[2 * p], a0);
                a1 = fmaf(kd, w[2 * p + 1], a1);
                a0 = a0 > 0.f ? a0 : 0.1f * a0;
                a1 = a1 > 0.f ? a1 : 0.1f * a1;
                pk[p] = pk_bf16(a0, a1);
            }
            uint4 o; o.x = pk[0]; o.y = pk[1]; o.z = pk[2]; o.w = pk[3];
            tout[q] = o;
        }
    }
    __syncthreads();

    // phase 2: MFMA. wave wv: rows (wv>>1)*32..+31, cols (wv&1)*64..+63.
    // B-fragments straight from global WbT (32KB, L1/L2-hot), reused x2 rows.
    int lane = tid & 63, wv = tid >> 6;
    int l15 = lane & 15, quad = lane >> 4;
    int ch = wv & 1, rh = wv >> 1;
    short8 afr[2][4];
#pragma unroll
    for (int rr = 0; rr < 2; ++rr) {
        const ushort* ab = sU + (rh * 32 + rr * 16 + l15) * 136 + quad * 8;
#pragma unroll
        for (int kc = 0; kc < 4; ++kc)
            afr[rr][kc] = *(const short8*)(ab + kc * 32);
    }
    f32x4 acc[2][4];
#pragma unroll
    for (int rr = 0; rr < 2; ++rr)
#pragma unroll
        for (int ct = 0; ct < 4; ++ct) acc[rr][ct] = (f32x4){0.f, 0.f, 0.f, 0.f};
#pragma unroll
    for (int kc = 0; kc < 4; ++kc) {
#pragma unroll
        for (int ct = 0; ct < 4; ++ct) {
            short8 bfr = *(const short8*)(WbT + ((ch * 4 + ct) * 16 + l15) * 128 + quad * 8 + kc * 32);
            acc[0][ct] = __builtin_amdgcn_mfma_f32_16x16x32_bf16(afr[0][kc], bfr, acc[0][ct], 0, 0, 0);
            acc[1][ct] = __builtin_amdgcn_mfma_f32_16x16x32_bf16(afr[1][kc], bfr, acc[1][ct], 0, 0, 0);
        }
    }
    __syncthreads();   // all t reads done -> sU reusable

    // epilogue: msgT[col][edge] bf16, stride 132
#pragma unroll
    for (int ct = 0; ct < 4; ++ct) {
        int col = (ch * 4 + ct) * 16 + l15;
#pragma unroll
        for (int rr = 0; rr < 2; ++rr) {
            uint2 pr;
            pr.x = pk_bf16(acc[rr][ct][0], acc[rr][ct][1]);
            pr.y = pk_bf16(acc[rr][ct][2], acc[rr][ct][3]);
            *(uint2*)(sU + col * 132 + rh * 32 + rr * 16 + quad * 4) = pr;
        }
    }
    __syncthreads();

    // phase 3: segmented max, 4 threads/col (quarter-window = 32 edges each)
    {
        int j = tid & 127;
        int q4 = tid >> 7;            // 0..3
        int eBeg = q4 * 32;
        const ushort* mrow = sU + j * 132 + eBeg;
        float vals[32];
#pragma unroll
        for (int q = 0; q < 8; ++q) {
            ushort4 mv = *(const ushort4*)(mrow + q * 4);
            vals[q * 4 + 0] = bf2f(mv.x);
            vals[q * 4 + 1] = bf2f(mv.y);
            vals[q * 4 + 2] = bf2f(mv.z);
            vals[q * 4 + 3] = bf2f(mv.w);
        }
        int prevD = (q4 == 0) ? ((w0 > 0) ? pedge[w0 - 1].y : -1) : sDst[eBeg - 1];
        int nextD = (q4 == 3) ? ((w0 + 128 < N_EDGES) ? pedge[w0 + 128].y : -1) : sDst[eBeg + 32];
        int cur = sDst[eBeg], rs = eBeg;
        float mx = vals[0];
        for (int e2 = 1; e2 < 32; ++e2) {
            int d = sDst[eBeg + e2];      // uniform across the quarter's lanes
            float vv2 = vals[e2];
            if (d != cur) {
                unsigned en = encf(mx);
                unsigned* ap = agg + (size_t)cur * HID + j;
                if (rs == eBeg && cur == prevD) atomicMax(ap, en);
                else *ap = en;
                cur = d; rs = eBeg + e2; mx = vv2;
            } else {
                mx = fmaxf(mx, vv2);
            }
        }
        unsigned en = encf(mx);
        unsigned* ap = agg + (size_t)cur * HID + j;
        if ((rs == eBeg && cur == prevD) || cur == nextD) atomicMax(ap, en);
        else *ap = en;
    }
}

// ---- pooling with fused layer-2 combine: x2 never materialized ----
__global__ __launch_bounds__(256) void pool_kernel(const ushort* __restrict__ x1,
                                                   const unsigned* __restrict__ agg2,
                                                   const float* __restrict__ b2b,
                                                   const int* __restrict__ cnt2,
                                                   const int* __restrict__ batch,
                                                   float* __restrict__ pooled) {
    int g = blockIdx.x >> 3, s = blockIdx.x & 7;
    int tid = threadIdx.x;
    int lo = 0, hi = N_NODES;
    while (lo < hi) { int mid = (lo + hi) >> 1; if (batch[mid] < g) lo = mid + 1; else hi = mid; }
    int start = lo;
    hi = N_NODES;
    while (lo < hi) { int mid = (lo + hi) >> 1; if (batch[mid] < g + 1) lo = mid + 1; else hi = mid; }
    int end = lo;
    int cnt = end - start;
    int b0 = start + (int)((long long)cnt * s / 8);
    int b1 = start + (int)((long long)cnt * (s + 1) / 8);
    if (b1 <= b0) return;
    int j = tid & 127;
    bool isx2 = tid >= 128;
    float bbj = isx2 ? b2b[j] : 0.f;
    float mx = -INFINITY, sm = 0.f;
    for (int n = b0; n < b1; ++n) {
        float xv = bf2f(x1[(size_t)n * HID + j]);
        float vv;
        if (isx2) {
            float a = 0.f;
            if (cnt2[n] > 0) a = decf(agg2[(size_t)n * HID + j]) + bbj;
            vv = fmaxf(a + xv, 0.f);
        } else {
            vv = xv;
        }
        mx = fmaxf(mx, vv);
        sm += vv;
    }
    atomicMax((unsigned*)pooled + (size_t)g * 512 + tid, encf(mx));
    atomicAdd(pooled + (size_t)g * 512 + 256 + tid, sm);
}

// ---- final MLP + log_softmax ----
__global__ __launch_bounds__(128) void final_kernel(const float* __restrict__ pooled,
                                                    const int* __restrict__ batch,
                                                    const float* __restrict__ Wf1,
                                                    const float* __restrict__ bf1,
                                                    const float* __restrict__ Wf2,
                                                    const float* __restrict__ bf2,
                                                    float* __restrict__ out) {
    __shared__ float sP[512];
    __shared__ float sH[128];
    int g = blockIdx.x, tid = threadIdx.x;
    int lo = 0, hi = N_NODES;
    while (lo < hi) { int mid = (lo + hi) >> 1; if (batch[mid] < g) lo = mid + 1; else hi = mid; }
    int start = lo;
    hi = N_NODES;
    while (lo < hi) { int mid = (lo + hi) >> 1; if (batch[mid] < g + 1) lo = mid + 1; else hi = mid; }
    int cnt = lo - start;
    float inv = 1.f / (float)(cnt > 1 ? cnt : 1);
#pragma unroll
    for (int q = 0; q < 4; ++q) {
        int idx = q * 128 + tid;
        float raw;
        if (idx < 256) {
            unsigned e = ((const unsigned*)pooled)[(size_t)g * 512 + idx];
            raw = (e == 0u) ? 0.f : decf(e);
        } else {
            raw = pooled[(size_t)g * 512 + idx] * inv;
        }
        sP[idx] = raw;
    }
    __syncthreads();
    float acc = bf1[tid];
    for (int k = 0; k < 512; ++k) acc = fmaf(sP[k], Wf1[k * HID + tid], acc);
    sH[tid] = fmaxf(acc, 0.f);
    __syncthreads();
    if (tid < 2) {
        float l = bf2[tid];
        for (int k = 0; k < 128; ++k) l = fmaf(sH[k], Wf2[k * 2 + tid], l);
        sP[tid] = l;
    }
    __syncthreads();
    if (tid == 0) {
        float l0 = sP[0], l1 = sP[1];
        float m = fmaxf(l0, l1);
        float ls = m + logf(expf(l0 - m) + expf(l1 - m));
        out[g * 2 + 0] = l0 - ls;
        out[g * 2 + 1] = l1 - ls;
    }
}

extern "C" void kernel_launch(void* const* d_in, const int* in_sizes, int n_in,
                              void* d_out, int out_size, void* d_ws, size_t ws_size,
                              hipStream_t stream) {
    const float* x     = (const float*)d_in[0];
    const float* W_enc = (const float*)d_in[1];
    const float* b_enc = (const float*)d_in[2];
    const float* W0    = (const float*)d_in[3];
    const float* b0    = (const float*)d_in[4];
    const float* W1a   = (const float*)d_in[5];
    const float* b1a   = (const float*)d_in[6];
    const float* W1b   = (const float*)d_in[7];
    const float* b1b   = (const float*)d_in[8];
    const float* W2a   = (const float*)d_in[9];
    const float* b2a   = (const float*)d_in[10];
    const float* W2b   = (const float*)d_in[11];
    const float* b2b   = (const float*)d_in[12];
    const float* Wf1   = (const float*)d_in[13];
    const float* bf1   = (const float*)d_in[14];
    const float* Wf2   = (const float*)d_in[15];
    const float* bf2   = (const float*)d_in[16];
    const int* src1    = (const int*)d_in[17];
    const int* dst1    = (const int*)d_in[18];
    const int* src2    = (const int*)d_in[19];
    const int* dst2    = (const int*)d_in[20];
    const int* batch   = (const int*)d_in[21];

    const size_t NB = (size_t)N_NODES * HID;     // 12.8M elements
    ushort* hbuf  = (ushort*)d_ws;               // h -> x1 (in place, bf16)
    unsigned* agg1 = (unsigned*)(hbuf + NB);     // layer-1 segment-max (u32 encoded)
    unsigned* agg2 = agg1 + NB;                  // layer-2 segment-max
    ushort* ubuf  = (ushort*)(agg2 + NB);        // u bf16
    ushort* vbuf  = ubuf + NB;                   // v bf16
    ushort* WT    = vbuf + NB;                   // 6 x 16384 bf16: Wb1,Wb2,Wu1,Wv1,Wu2,Wv2
    ushort* WbT1 = WT;
    ushort* WbT2 = WT + 1 * HID * HID;
    ushort* WuT1 = WT + 2 * HID * HID;
    ushort* WvT1 = WT + 3 * HID * HID;
    ushort* WuT2 = WT + 4 * HID * HID;
    ushort* WvT2 = WT + 5 * HID * HID;
    float* wkey  = (float*)(WT + 6 * HID * HID);
    float* bias0 = wkey + 128;
    float* pooled = bias0 + 128;                 // 128*512 fp32
    int* cnt    = (int*)(pooled + 128 * 512);    // 2*N_NODES (both layers)
    int* cursor = cnt + 2 * N_NODES;             // 2*N_NODES
    int* partials = cursor + 2 * N_NODES;        // 1024
    int2* pedge = (int2*)(partials + 1024);      // 2*N_EDGES pairs (both layers)

    const int bothGrid = (2 * N_EDGES + 255) / 256;   // 3907
    const int edgeGrid = (N_EDGES + 127) / 128;       // 3907 windows of 128
    const int mmGrid   = (N_NODES + 127) / 128;       // 782
    const int zbGrid   = (2 * N_HALF + 3) / 4;        // 7813 (both layers)
    const int prepGrid = 385 + SCAN1_B + 256;         // transpose+prep+zero(cnt,pooled)

    transp_prep_kernel<<<prepGrid, 256, 0, stream>>>(W1b, W2b, W1a, W2a, W_enc, b_enc, W0, b0,
                                                     WT, wkey, bias0, cnt, pooled);
    encode_kernel<<<N_NODES / 2, 256, 0, stream>>>(x, W0, wkey, bias0, hbuf);

    // ---- merged CSR build (both layers; cnt zeroed by transp_prep) ----
    hist_kernel<<<bothGrid, 256, 0, stream>>>(dst1, dst2, cnt);
    scan1_kernel<<<SCAN1_B, 256, 0, stream>>>(cnt, cursor, partials);
    scan2_kernel<<<1, 1024, 0, stream>>>(partials);
    scatter_kernel<<<bothGrid, 256, 0, stream>>>(src1, dst1, src2, dst2, cursor, partials, pedge);
    zbound_both_kernel<<<zbGrid, 256, 0, stream>>>(pedge, agg1, agg2);

    // ---- layer 1 ----
    mm_mfma_dual_kernel<<<mmGrid, 256, 0, stream>>>(hbuf, nullptr, nullptr, nullptr, nullptr,
                                                    WuT1, WvT1, b1a, ubuf, vbuf, N_NODES);
    edge_kernel<<<edgeGrid, 512, 0, stream>>>(ubuf, vbuf, x, pedge, WbT1, W1a + 256 * HID, agg1);

    // ---- layer 2 (mm fuses layer-1 combine; writes x1 to hbuf) ----
    mm_mfma_dual_kernel<<<mmGrid, 256, 0, stream>>>(hbuf, agg1, cnt, b1b, hbuf,
                                                    WuT2, WvT2, b2a, ubuf, vbuf, N_NODES);
    edge_kernel<<<edgeGrid, 512, 0, stream>>>(ubuf, vbuf, x, pedge + N_EDGES, WbT2, W2a + 256 * HID, agg2);

    // ---- pooling (layer-2 combine fused; pooled zeroed by transp_prep) + head ----
    pool_kernel<<<N_GRAPHS * 8, 256, 0, stream>>>(hbuf, agg2, b2b, cnt + N_NODES, batch, pooled);
    final_kernel<<<N_GRAPHS, 128, 0, stream>>>(pooled, batch, Wf1, bf1, Wf2, bf2, (float*)d_out);
}

// Round 2
// 658.852 us; speedup vs baseline: 1.0681x; 1.0681x over previous
//
#include <hip/hip_runtime.h>
#include <cstdint>

#define N_NODES 100000
#define N_EDGES 500000
#define N_GRAPHS 128
#define HID 128
#define SCAN1_B ((2 * N_NODES + 255) / 256)   // 782 blocks over concatenated counts
#define N_SEG (N_EDGES / 16)                  // 31250 16-edge segments per layer (phase-3 quarter granularity)

typedef __attribute__((ext_vector_type(8))) short short8;
typedef __attribute__((ext_vector_type(4))) float f32x4;

// ---- monotone float<->uint encoding for max; enc==0 marks "never written" ----
__device__ __forceinline__ unsigned encf(float f) {
    unsigned u = __float_as_uint(f);
    return (u & 0x80000000u) ? ~u : (u | 0x80000000u);
}
__device__ __forceinline__ float decf(unsigned e) {
    unsigned u = (e & 0x80000000u) ? (e & 0x7FFFFFFFu) : ~e;
    return __uint_as_float(u);
}
__device__ __forceinline__ unsigned pk_bf16(float a, float b) {
    unsigned ua = __float_as_uint(a);
    unsigned ub = __float_as_uint(b);
    ua = (ua + 0x7fffu + ((ua >> 16) & 1u)) >> 16;
    ub = (ub + 0x7fffu + ((ub >> 16) & 1u)) & 0xffff0000u;
    return ua | ub;
}
__device__ __forceinline__ ushort bf16r(float f) {
    unsigned u = __float_as_uint(f);
    return (ushort)((u + 0x7fffu + ((u >> 16) & 1u)) >> 16);
}
__device__ __forceinline__ float bf2f(ushort h) {
    return __uint_as_float((unsigned)h << 16);
}

// ---- transpose+convert weights -> bf16 [n][k], D computed on the fly;
//      block 384 does the prep (wkey/bias0); blocks >=385 zero cnt + pooled ----
__global__ __launch_bounds__(256) void transp_prep_kernel(const float* __restrict__ W1b,
                                                          const float* __restrict__ W2b,
                                                          const float* __restrict__ W1a,
                                                          const float* __restrict__ W2a,
                                                          const float* __restrict__ W_enc,
                                                          const float* __restrict__ b_enc,
                                                          const float* __restrict__ W0,
                                                          const float* __restrict__ b0,
                                                          ushort* __restrict__ WT,
                                                          float* __restrict__ wkey,
                                                          float* __restrict__ bias0,
                                                          int* __restrict__ cnt,
                                                          float* __restrict__ pooled) {
    int blk = blockIdx.x;
    int tid = threadIdx.x;
    if (blk >= 385) {   // zeroing duty: 782 blocks for cnt, 256 for pooled
        int z = blk - 385;
        if (z < SCAN1_B) {
            int i = z * 256 + tid;
            if (i < 2 * N_NODES) cnt[i] = 0;
        } else {
            int i = (z - SCAN1_B) * 256 + tid;   // exactly 128*512 = 65536 floats
            pooled[i] = 0.f;
        }
        return;
    }
    if (blk == 384) {   // prep
        if (tid < HID) {
            float wk = 0.f, bk = b0[tid];
            for (int k = 0; k < 32; ++k) {
                float w = W0[(15 + k) * HID + tid];
                wk += W_enc[k] * w;
                bk += b_enc[k] * w;
            }
            wkey[tid] = wk;
            bias0[tid] = bk;
        }
        return;
    }
    int m = blk >> 6;
    int i = (blk & 63) * 256 + tid;   // i = n*128 + k
    int n = i >> 7, k = i & 127;
    int src = k * HID + n;
    float v;
    switch (m) {
        case 0: v = W1b[src]; break;
        case 1: v = W2b[src]; break;
        case 2: v = W1a[src]; break;
        case 3: v = W1a[HID * HID + src] - W1a[src]; break;
        case 4: v = W2a[src]; break;
        default: v = W2a[HID * HID + src] - W2a[src]; break;
    }
    WT[m * HID * HID + i] = bf16r(v);
}

// ---- encoder: h = relu(features @ W0[0:15] + key*wkey + bias0) -> bf16 ----
__global__ __launch_bounds__(256) void encode_kernel(const float* __restrict__ x,
                                                     const float* __restrict__ W0,
                                                     const float* __restrict__ wkey,
                                                     const float* __restrict__ bias0,
                                                     ushort* __restrict__ h) {
    int n = blockIdx.x * 2 + (threadIdx.x >> 7);
    int j = threadIdx.x & 127;
    const float* xr = x + n * 16;
    float acc = bias0[j] + xr[0] * wkey[j];
#pragma unroll
    for (int f = 0; f < 15; ++f)
        acc = fmaf(xr[1 + f], W0[f * HID + j], acc);
    h[n * HID + j] = bf16r(fmaxf(acc, 0.f));
}

// ---- dual MFMA (N x 128 bf16) @ (128 x 128) -> bf16, LDS-restaged epilogue ----
__global__ __launch_bounds__(256, 4) void mm_mfma_dual_kernel(const ushort* __restrict__ in,
                                                              const unsigned* __restrict__ aggin,
                                                              const int* __restrict__ cntin,
                                                              const float* __restrict__ baddin,
                                                              ushort* __restrict__ xout,
                                                              const ushort* __restrict__ WuT,
                                                              const ushort* __restrict__ WvT,
                                                              const float* __restrict__ bv,
                                                              ushort* __restrict__ outu,
                                                              ushort* __restrict__ outv, int nrows) {
    __shared__ ushort sH[128 * 136];   // A-tile, then reused for D-restage
    int tid = threadIdx.x;
    int n0 = blockIdx.x * 128;
#pragma unroll
    for (int q = 0; q < 8; ++q) {
        int c = q * 256 + tid;
        int r = c >> 4, off = (c & 15) << 3;
        int n = n0 + r;
        uint4 vv = make_uint4(0, 0, 0, 0);
        if (n < nrows) {
            uint4 hv = *(const uint4*)(in + (size_t)n * HID + off);
            if (aggin) {
                float add[8];
#pragma unroll
                for (int p = 0; p < 8; ++p) add[p] = 0.f;
                if (cntin[n] > 0) {
                    uint4 e0 = *(const uint4*)(aggin + (size_t)n * HID + off);
                    uint4 e1 = *(const uint4*)(aggin + (size_t)n * HID + off + 4);
                    float4 bb0 = *(const float4*)(baddin + off);
                    float4 bb1 = *(const float4*)(baddin + off + 4);
                    add[0] = decf(e0.x) + bb0.x; add[1] = decf(e0.y) + bb0.y;
                    add[2] = decf(e0.z) + bb0.z; add[3] = decf(e0.w) + bb0.w;
                    add[4] = decf(e1.x) + bb1.x; add[5] = decf(e1.y) + bb1.y;
                    add[6] = decf(e1.z) + bb1.z; add[7] = decf(e1.w) + bb1.w;
                }
                unsigned hw[4] = {hv.x, hv.y, hv.z, hv.w};
                unsigned ow[4];
#pragma unroll
                for (int p = 0; p < 4; ++p) {
                    float lo = __uint_as_float(hw[p] << 16);
                    float hi = __uint_as_float(hw[p] & 0xffff0000u);
                    float r0 = fmaxf(add[2 * p] + lo, 0.f);
                    float r1 = fmaxf(add[2 * p + 1] + hi, 0.f);
                    ow[p] = pk_bf16(r0, r1);
                }
                vv = make_uint4(ow[0], ow[1], ow[2], ow[3]);
                *(uint4*)(xout + (size_t)n * HID + off) = vv;
            } else {
                vv = hv;
            }
        }
        *(uint4*)(sH + r * 136 + off) = vv;
    }
    __syncthreads();

    int lane = tid & 63, wv = tid >> 6;
    int l15 = lane & 15, quad = lane >> 4;

    short8 afr[2][4];
#pragma unroll
    for (int rr = 0; rr < 2; ++rr) {
        const ushort* ab = sH + (wv * 32 + rr * 16 + l15) * 136 + quad * 8;
#pragma unroll
        for (int kc = 0; kc < 4; ++kc)
            afr[rr][kc] = *(const short8*)(ab + kc * 32);
    }

#pragma unroll
    for (int pass = 0; pass < 2; ++pass) {
        const ushort* WT = pass ? WvT : WuT;
        ushort* out = pass ? outv : outu;
        f32x4 acc[2][8];
#pragma unroll
        for (int rr = 0; rr < 2; ++rr)
#pragma unroll
            for (int ct = 0; ct < 8; ++ct) acc[rr][ct] = (f32x4){0.f, 0.f, 0.f, 0.f};
#pragma unroll
        for (int kc = 0; kc < 4; ++kc) {
#pragma unroll
            for (int ct = 0; ct < 8; ++ct) {
                short8 bfr = *(const short8*)(WT + (ct * 16 + l15) * 128 + quad * 8 + kc * 32);
                acc[0][ct] = __builtin_amdgcn_mfma_f32_16x16x32_bf16(afr[0][kc], bfr, acc[0][ct], 0, 0, 0);
                acc[1][ct] = __builtin_amdgcn_mfma_f32_16x16x32_bf16(afr[1][kc], bfr, acc[1][ct], 0, 0, 0);
            }
        }
        __syncthreads();
#pragma unroll
        for (int ct = 0; ct < 8; ++ct) {
            int col = ct * 16 + l15;
            float bb = pass ? bv[col] : 0.f;
#pragma unroll
            for (int rr = 0; rr < 2; ++rr) {
                int rowb = wv * 32 + rr * 16 + quad * 4;
#pragma unroll
                for (int reg = 0; reg < 4; ++reg)
                    sH[(rowb + reg) * 136 + col] = bf16r(acc[rr][ct][reg] + bb);
            }
        }
        __syncthreads();
#pragma unroll
        for (int q = 0; q < 8; ++q) {
            int c = q * 256 + tid;
            int r = c >> 4, off = (c & 15) << 3;
            int m = n0 + r;
            if (m < nrows)
                *(uint4*)(out + (size_t)m * HID + off) = *(const uint4*)(sH + r * 136 + off);
        }
    }
}

// ---- merged CSR build for BOTH layers ----
__global__ __launch_bounds__(256) void hist_kernel(const int* __restrict__ dst1,
                                                   const int* __restrict__ dst2,
                                                   int* __restrict__ cnt) {
    int e = blockIdx.x * 256 + threadIdx.x;
    if (e < N_EDGES) atomicAdd(&cnt[dst1[e]], 1);
    else if (e < 2 * N_EDGES) atomicAdd(&cnt[N_NODES + dst2[e - N_EDGES]], 1);
}

__global__ __launch_bounds__(256) void scan1_kernel(const int* __restrict__ cnt,
                                                    int* __restrict__ cursor,
                                                    int* __restrict__ partials) {
    __shared__ int tmp[256];
    int tid = threadIdx.x;
    int gid = blockIdx.x * 256 + tid;
    int v = (gid < 2 * N_NODES) ? cnt[gid] : 0;
    tmp[tid] = v;
    __syncthreads();
#pragma unroll
    for (int off = 1; off < 256; off <<= 1) {
        int t = (tid >= off) ? tmp[tid - off] : 0;
        __syncthreads();
        tmp[tid] += t;
        __syncthreads();
    }
    if (gid < 2 * N_NODES) cursor[gid] = tmp[tid] - v;   // local exclusive
    if (tid == 255) partials[blockIdx.x] = tmp[255];
}

__global__ __launch_bounds__(1024) void scan2_kernel(int* __restrict__ partials) {
    __shared__ int tmp[1024];
    int tid = threadIdx.x;
    int v = (tid < SCAN1_B) ? partials[tid] : 0;
    tmp[tid] = v;
    __syncthreads();
#pragma unroll
    for (int off = 1; off < 1024; off <<= 1) {
        int t = (tid >= off) ? tmp[tid - off] : 0;
        __syncthreads();
        tmp[tid] += t;
        __syncthreads();
    }
    if (tid < SCAN1_B) partials[tid] = tmp[tid] - v;  // exclusive
}

__global__ __launch_bounds__(256) void scatter_kernel(const int* __restrict__ src1,
                                                      const int* __restrict__ dst1,
                                                      const int* __restrict__ src2,
                                                      const int* __restrict__ dst2,
                                                      int* __restrict__ cursor,
                                                      const int* __restrict__ partials,
                                                      int2* __restrict__ pedge) {
    int e = blockIdx.x * 256 + threadIdx.x;
    if (e < N_EDGES) {
        int d = dst1[e];
        int pos = atomicAdd(&cursor[d], 1) + partials[d >> 8];
        pedge[pos] = make_int2(src1[e], d);
    } else if (e < 2 * N_EDGES) {
        int d = dst2[e - N_EDGES];
        int idx = N_NODES + d;
        int pos = atomicAdd(&cursor[idx], 1) + partials[idx >> 8];
        pedge[pos] = make_int2(src2[e - N_EDGES], d);   // pos lands in [N_EDGES, 2*N_EDGES)
    }
}

// ---- zero boundary agg rows for BOTH layers in one launch (u32 arrays).
//      16-edge granularity to match the phase-3 quarter size at window=64 ----
__global__ __launch_bounds__(256) void zbound_both_kernel(const int2* __restrict__ pedge,
                                                          unsigned* __restrict__ agg1,
                                                          unsigned* __restrict__ agg2) {
    int b = blockIdx.x * 4 + (threadIdx.x >> 6);
    int lane = threadIdx.x & 63;
    if (b >= 2 * N_SEG) return;
    int layer = b >= N_SEG;
    int bl = b - layer * N_SEG;
    const int2* pe = pedge + (size_t)layer * N_EDGES;
    unsigned* agg = layer ? agg2 : agg1;
    int d;
    if (bl == 0) {
        d = pe[N_EDGES - 1].y;               // tail row (clamped duplicates -> atomics)
    } else {
        int da = pe[bl * 16 - 1].y, db = pe[bl * 16].y;
        if (da != db) return;
        d = db;
    }
    *(uint2*)(agg + (size_t)d * HID + lane * 2) = make_uint2(0u, 0u);
}

// ---- edge conv: bf16 MFMA, 64-edge dst-sorted windows, 512 threads ----
// v3: LDS W-tile restored (R1's global-W B-reads were latency-bound);
//     window 128->64 shrinks sU so LDS = 52.5 KB -> 3 blocks/CU (24 waves)
//     at __launch_bounds__(512,6). Per-thread pedge meta kept from v2
//     (no meta barrier); kd via intra-group shfl (2 x-loads per edge).
__global__ __launch_bounds__(512, 6) void edge_kernel(const ushort* __restrict__ u,
                                                      const ushort* __restrict__ v,
                                                      const float* __restrict__ x,
                                                      const int2* __restrict__ pedge,
                                                      const ushort* __restrict__ WbT,
                                                      const float* __restrict__ wlast,
                                                      unsigned* __restrict__ agg) {
    __shared__ ushort sWT[128 * 136];   // 34816 B: WbT[n][k] bf16, padded stride
    __shared__ ushort sU[64 * 136];     // 17408 B union: t[64][136] then msgT[128][66]
    __shared__ int sDst[64];
    int tid = threadIdx.x;
    int w0 = blockIdx.x * 64;

    // W stage: 2048 uint4 over 512 threads = 4 each (L2-hot 32KB)
#pragma unroll
    for (int q = 0; q < 4; ++q) {
        int c = q * 512 + tid;
        int n = c >> 4, off = (c & 15) << 3;
        *(uint4*)(sWT + n * 136 + off) = *(const uint4*)(WbT + n * 128 + off);
    }

    // phase 1: 8 threads/edge, 16 cols each; meta via per-thread pedge + shfl
    {
        int eloc = tid >> 3;
        int sub = tid & 7;
        int kb = sub << 4;
        int e = w0 + eloc;
        if (e >= N_EDGES) e = N_EDGES - 1;   // clamp: idempotent under max (tail row pre-zeroed)
        int2 sd = pedge[e];
        if (sub == 0) sDst[eloc] = sd.y;
        float kx = 0.f;
        if (sub < 2) kx = x[(size_t)(sub ? sd.y : sd.x) * 16];
        int lane_ = tid & 63;
        int grp = lane_ & ~7;
        float kd = __shfl(kx, grp, 64) - __shfl(kx, grp + 1, 64);
        const uint4* ur = (const uint4*)(u + (size_t)sd.x * HID + kb);
        const uint4* vr = (const uint4*)(v + (size_t)sd.y * HID + kb);
        uint4 uu[2], vv[2];
        uu[0] = ur[0]; uu[1] = ur[1];
        vv[0] = vr[0]; vv[1] = vr[1];
        const float4* wr4 = (const float4*)(wlast + kb);
        uint4* tout = (uint4*)(sU + eloc * 136 + kb);
#pragma unroll
        for (int q = 0; q < 2; ++q) {
            float4 wa = wr4[2 * q], wb = wr4[2 * q + 1];
            float w[8] = {wa.x, wa.y, wa.z, wa.w, wb.x, wb.y, wb.z, wb.w};
            unsigned pu[4] = {uu[q].x, uu[q].y, uu[q].z, uu[q].w};
            unsigned pv[4] = {vv[q].x, vv[q].y, vv[q].z, vv[q].w};
            unsigned pk[4];
#pragma unroll
            for (int p = 0; p < 4; ++p) {
                float a0 = __uint_as_float(pu[p] << 16) + __uint_as_float(pv[p] << 16);
                float a1 = __uint_as_float(pu[p] & 0xffff0000u) + __uint_as_float(pv[p] & 0xffff0000u);
                a0 = fmaf(kd, w[2 * p], a0);
                a1 = fmaf(kd, w[2 * p + 1], a1);
                a0 = a0 > 0.f ? a0 : 0.1f * a0;
                a1 = a1 > 0.f ? a1 : 0.1f * a1;
                pk[p] = pk_bf16(a0, a1);
            }
            uint4 o; o.x = pk[0]; o.y = pk[1]; o.z = pk[2]; o.w = pk[3];
            tout[q] = o;
        }
    }
    __syncthreads();   // covers W-stage + t + sDst

    // phase 2: MFMA. wave wv: rows (wv>>1)*16..+15, cols (wv&1)*64..+63
    int lane = tid & 63, wv = tid >> 6;
    int l15 = lane & 15, quad = lane >> 4;
    int ch = wv & 1, rh = wv >> 1;
    short8 afr[4];
    {
        const ushort* ab = sU + (rh * 16 + l15) * 136 + quad * 8;
#pragma unroll
        for (int kc = 0; kc < 4; ++kc)
            afr[kc] = *(const short8*)(ab + kc * 32);
    }
    f32x4 acc[4];
#pragma unroll
    for (int ct = 0; ct < 4; ++ct) acc[ct] = (f32x4){0.f, 0.f, 0.f, 0.f};
#pragma unroll
    for (int kc = 0; kc < 4; ++kc) {
#pragma unroll
        for (int ct = 0; ct < 4; ++ct) {
            short8 bfr = *(const short8*)(sWT + ((ch * 4 + ct) * 16 + l15) * 136 + quad * 8 + kc * 32);
            acc[ct] = __builtin_amdgcn_mfma_f32_16x16x32_bf16(afr[kc], bfr, acc[ct], 0, 0, 0);
        }
    }
    __syncthreads();   // all t reads done -> sU reusable

    // epilogue: msgT[col][edge] bf16, stride 66 (odd dword stride -> conflict-free)
#pragma unroll
    for (int ct = 0; ct < 4; ++ct) {
        int col = (ch * 4 + ct) * 16 + l15;
        uint2 pr;
        pr.x = pk_bf16(acc[ct][0], acc[ct][1]);
        pr.y = pk_bf16(acc[ct][2], acc[ct][3]);
        *(uint2*)(sU + col * 66 + rh * 16 + quad * 4) = pr;
    }
    __syncthreads();

    // phase 3: segmented max, 4 threads/col (quarter-window = 16 edges each)
    {
        int j = tid & 127;
        int q4 = tid >> 7;            // 0..3
        int eBeg = q4 * 16;
        const ushort* mrow = sU + j * 66 + eBeg;
        float vals[16];
#pragma unroll
        for (int q = 0; q < 4; ++q) {
            ushort4 mv = *(const ushort4*)(mrow + q * 4);
            vals[q * 4 + 0] = bf2f(mv.x);
            vals[q * 4 + 1] = bf2f(mv.y);
            vals[q * 4 + 2] = bf2f(mv.z);
            vals[q * 4 + 3] = bf2f(mv.w);
        }
        int prevD = (q4 == 0) ? ((w0 > 0) ? pedge[w0 - 1].y : -1) : sDst[eBeg - 1];
        int nextD = (q4 == 3) ? ((w0 + 64 < N_EDGES) ? pedge[w0 + 64].y : -1) : sDst[eBeg + 16];
        int cur = sDst[eBeg], rs = eBeg;
        float mx = vals[0];
        for (int e2 = 1; e2 < 16; ++e2) {
            int d = sDst[eBeg + e2];      // uniform across the quarter's lanes
            float vv2 = vals[e2];
            if (d != cur) {
                unsigned en = encf(mx);
                unsigned* ap = agg + (size_t)cur * HID + j;
                if (rs == eBeg && cur == prevD) atomicMax(ap, en);
                else *ap = en;
                cur = d; rs = eBeg + e2; mx = vv2;
            } else {
                mx = fmaxf(mx, vv2);
            }
        }
        unsigned en = encf(mx);
        unsigned* ap = agg + (size_t)cur * HID + j;
        if ((rs == eBeg && cur == prevD) || cur == nextD) atomicMax(ap, en);
        else *ap = en;
    }
}

// ---- pooling with fused layer-2 combine: x2 never materialized ----
__global__ __launch_bounds__(256) void pool_kernel(const ushort* __restrict__ x1,
                                                   const unsigned* __restrict__ agg2,
                                                   const float* __restrict__ b2b,
                                                   const int* __restrict__ cnt2,
                                                   const int* __restrict__ batch,
                                                   float* __restrict__ pooled) {
    int g = blockIdx.x >> 3, s = blockIdx.x & 7;
    int tid = threadIdx.x;
    int lo = 0, hi = N_NODES;
    while (lo < hi) { int mid = (lo + hi) >> 1; if (batch[mid] < g) lo = mid + 1; else hi = mid; }
    int start = lo;
    hi = N_NODES;
    while (lo < hi) { int mid = (lo + hi) >> 1; if (batch[mid] < g + 1) lo = mid + 1; else hi = mid; }
    int end = lo;
    int cnt = end - start;
    int b0 = start + (int)((long long)cnt * s / 8);
    int b1 = start + (int)((long long)cnt * (s + 1) / 8);
    if (b1 <= b0) return;
    int j = tid & 127;
    bool isx2 = tid >= 128;
    float bbj = isx2 ? b2b[j] : 0.f;
    float mx = -INFINITY, sm = 0.f;
    for (int n = b0; n < b1; ++n) {
        float xv = bf2f(x1[(size_t)n * HID + j]);
        float vv;
        if (isx2) {
            float a = 0.f;
            if (cnt2[n] > 0) a = decf(agg2[(size_t)n * HID + j]) + bbj;
            vv = fmaxf(a + xv, 0.f);
        } else {
            vv = xv;
        }
        mx = fmaxf(mx, vv);
        sm += vv;
    }
    atomicMax((unsigned*)pooled + (size_t)g * 512 + tid, encf(mx));
    atomicAdd(pooled + (size_t)g * 512 + 256 + tid, sm);
}

// ---- final MLP + log_softmax ----
__global__ __launch_bounds__(128) void final_kernel(const float* __restrict__ pooled,
                                                    const int* __restrict__ batch,
                                                    const float* __restrict__ Wf1,
                                                    const float* __restrict__ bf1,
                                                    const float* __restrict__ Wf2,
                                                    const float* __restrict__ bf2,
                                                    float* __restrict__ out) {
    __shared__ float sP[512];
    __shared__ float sH[128];
    int g = blockIdx.x, tid = threadIdx.x;
    int lo = 0, hi = N_NODES;
    while (lo < hi) { int mid = (lo + hi) >> 1; if (batch[mid] < g) lo = mid + 1; else hi = mid; }
    int start = lo;
    hi = N_NODES;
    while (lo < hi) { int mid = (lo + hi) >> 1; if (batch[mid] < g + 1) lo = mid + 1; else hi = mid; }
    int cnt = lo - start;
    float inv = 1.f / (float)(cnt > 1 ? cnt : 1);
#pragma unroll
    for (int q = 0; q < 4; ++q) {
        int idx = q * 128 + tid;
        float raw;
        if (idx < 256) {
            unsigned e = ((const unsigned*)pooled)[(size_t)g * 512 + idx];
            raw = (e == 0u) ? 0.f : decf(e);
        } else {
            raw = pooled[(size_t)g * 512 + idx] * inv;
        }
        sP[idx] = raw;
    }
    __syncthreads();
    float acc = bf1[tid];
    for (int k = 0; k < 512; ++k) acc = fmaf(sP[k], Wf1[k * HID + tid], acc);
    sH[tid] = fmaxf(acc, 0.f);
    __syncthreads();
    if (tid < 2) {
        float l = bf2[tid];
        for (int k = 0; k < 128; ++k) l = fmaf(sH[k], Wf2[k * 2 + tid], l);
        sP[tid] = l;
    }
    __syncthreads();
    if (tid == 0) {
        float l0 = sP[0], l1 = sP[1];
        float m = fmaxf(l0, l1);
        float ls = m + logf(expf(l0 - m) + expf(l1 - m));
        out[g * 2 + 0] = l0 - ls;
        out[g * 2 + 1] = l1 - ls;
    }
}

extern "C" void kernel_launch(void* const* d_in, const int* in_sizes, int n_in,
                              void* d_out, int out_size, void* d_ws, size_t ws_size,
                              hipStream_t stream) {
    const float* x     = (const float*)d_in[0];
    const float* W_enc = (const float*)d_in[1];
    const float* b_enc = (const float*)d_in[2];
    const float* W0    = (const float*)d_in[3];
    const float* b0    = (const float*)d_in[4];
    const float* W1a   = (const float*)d_in[5];
    const float* b1a   = (const float*)d_in[6];
    const float* W1b   = (const float*)d_in[7];
    const float* b1b   = (const float*)d_in[8];
    const float* W2a   = (const float*)d_in[9];
    const float* b2a   = (const float*)d_in[10];
    const float* W2b   = (const float*)d_in[11];
    const float* b2b   = (const float*)d_in[12];
    const float* Wf1   = (const float*)d_in[13];
    const float* bf1   = (const float*)d_in[14];
    const float* Wf2   = (const float*)d_in[15];
    const float* bf2   = (const float*)d_in[16];
    const int* src1    = (const int*)d_in[17];
    const int* dst1    = (const int*)d_in[18];
    const int* src2    = (const int*)d_in[19];
    const int* dst2    = (const int*)d_in[20];
    const int* batch   = (const int*)d_in[21];

    const size_t NB = (size_t)N_NODES * HID;     // 12.8M elements
    ushort* hbuf  = (ushort*)d_ws;               // h -> x1 (in place, bf16)
    unsigned* agg1 = (unsigned*)(hbuf + NB);     // layer-1 segment-max (u32 encoded)
    unsigned* agg2 = agg1 + NB;                  // layer-2 segment-max
    ushort* ubuf  = (ushort*)(agg2 + NB);        // u bf16
    ushort* vbuf  = ubuf + NB;                   // v bf16
    ushort* WT    = vbuf + NB;                   // 6 x 16384 bf16: Wb1,Wb2,Wu1,Wv1,Wu2,Wv2
    ushort* WbT1 = WT;
    ushort* WbT2 = WT + 1 * HID * HID;
    ushort* WuT1 = WT + 2 * HID * HID;
    ushort* WvT1 = WT + 3 * HID * HID;
    ushort* WuT2 = WT + 4 * HID * HID;
    ushort* WvT2 = WT + 5 * HID * HID;
    float* wkey  = (float*)(WT + 6 * HID * HID);
    float* bias0 = wkey + 128;
    float* pooled = bias0 + 128;                 // 128*512 fp32
    int* cnt    = (int*)(pooled + 128 * 512);    // 2*N_NODES (both layers)
    int* cursor = cnt + 2 * N_NODES;             // 2*N_NODES
    int* partials = cursor + 2 * N_NODES;        // 1024
    int2* pedge = (int2*)(partials + 1024);      // 2*N_EDGES pairs (both layers)

    const int bothGrid = (2 * N_EDGES + 255) / 256;   // 3907
    const int edgeGrid = (N_EDGES + 63) / 64;         // 7813 windows of 64
    const int mmGrid   = (N_NODES + 127) / 128;       // 782
    const int zbGrid   = (2 * N_SEG + 3) / 4;         // 15626 (both layers, 16-edge granularity)
    const int prepGrid = 385 + SCAN1_B + 256;         // transpose+prep+zero(cnt,pooled)

    transp_prep_kernel<<<prepGrid, 256, 0, stream>>>(W1b, W2b, W1a, W2a, W_enc, b_enc, W0, b0,
                                                     WT, wkey, bias0, cnt, pooled);
    encode_kernel<<<N_NODES / 2, 256, 0, stream>>>(x, W0, wkey, bias0, hbuf);

    // ---- merged CSR build (both layers; cnt zeroed by transp_prep) ----
    hist_kernel<<<bothGrid, 256, 0, stream>>>(dst1, dst2, cnt);
    scan1_kernel<<<SCAN1_B, 256, 0, stream>>>(cnt, cursor, partials);
    scan2_kernel<<<1, 1024, 0, stream>>>(partials);
    scatter_kernel<<<bothGrid, 256, 0, stream>>>(src1, dst1, src2, dst2, cursor, partials, pedge);
    zbound_both_kernel<<<zbGrid, 256, 0, stream>>>(pedge, agg1, agg2);

    // ---- layer 1 ----
    mm_mfma_dual_kernel<<<mmGrid, 256, 0, stream>>>(hbuf, nullptr, nullptr, nullptr, nullptr,
                                                    WuT1, WvT1, b1a, ubuf, vbuf, N_NODES);
    edge_kernel<<<edgeGrid, 512, 0, stream>>>(ubuf, vbuf, x, pedge, WbT1, W1a + 256 * HID, agg1);

    // ---- layer 2 (mm fuses layer-1 combine; writes x1 to hbuf) ----
    mm_mfma_dual_kernel<<<mmGrid, 256, 0, stream>>>(hbuf, agg1, cnt, b1b, hbuf,
                                                    WuT2, WvT2, b2a, ubuf, vbuf, N_NODES);
    edge_kernel<<<edgeGrid, 512, 0, stream>>>(ubuf, vbuf, x, pedge + N_EDGES, WbT2, W2a + 256 * HID, agg2);

    // ---- pooling (layer-2 combine fused; pooled zeroed by transp_prep) + head ----
    pool_kernel<<<N_GRAPHS * 8, 256, 0, stream>>>(hbuf, agg2, b2b, cnt + N_NODES, batch, pooled);
    final_kernel<<<N_GRAPHS, 128, 0, stream>>>(pooled, batch, Wf1, bf1, Wf2, bf2, (float*)d_out);
}